// Round 7
// baseline (37.667 us; speedup 1.0000x reference)
//
#include <hip/hip_runtime.h>
#include <hip/hip_bf16.h>
#include <math.h>

#define D 256
#define NPROTO 1024
#define WR 13
#define WC 18
#define WJ (WR * WC)
#define JSUB 59                    // ceil(WJ/4)
#define GMAT_BLOCKS 256            // 4 protos each
#define XPREP_BLOCKS 512           // 32 rows each

typedef __attribute__((ext_vector_type(8))) short short8;
typedef __attribute__((ext_vector_type(4))) float f32x4;

__device__ __forceinline__ short f2bf(float f) {
    union { __hip_bfloat16 b; short s; } u;
    u.b = __float2bfloat16(f);
    return u.s;
}

// ---- hex-grid neighborhood H[i,j] on the fly (fp64, matches np ref) ----
__device__ __forceinline__ void proto_pos(int idx, double& x, double& y) {
    int r = idx >> 5, c = idx & 31;
    x = (double)c + 0.5 * (double)(r & 1);
    y = (double)r * 0.86602540378443864676;  // sqrt(3)/2
}

__device__ __forceinline__ float hval(int i, int j) {
    double xi, yi, xj, yj;
    proto_pos(i, xi, yi);
    proto_pos(j, xj, yj);
    double dx0 = xi - xj, dy0 = yi - yj;
    const double W = 32.0;
    const double Hh = 27.712812921102035;  // 32*sqrt(3)/2
    double best = 1e300;
#pragma unroll
    for (int sx = -1; sx <= 1; ++sx) {
        double dx = dx0 + (double)sx * W;
#pragma unroll
        for (int sy = -1; sy <= 1; ++sy) {
            double dy = dy0 + (double)sy * Hh;
            double d2 = dx * dx + dy * dy;
            best = fmin(best, d2);
        }
    }
    return (float)exp(-0.5 * best);
}

// Fragment tile layout (shared by XgF and GbF): tile (Rg = row>>4, kg = k>>5)
// occupies 512 shorts at (Rg*8 + kg)*512; position ((row&15) + 16*q)*8 holds
// row's elements k = kg*32 + q*8 .. +7. MFMA A/B lane map: row = l&15,
// k-sub = l>>4. Verified end-to-end in R6 (GbF path passed).

// ---- prep: role-split.
//  bx < 256:  gmat — GbF = bf16(H@P) fragment-ordered + hsum + hp2
//  bx >= 256: xprep — XgF = bf16(X) fragment-ordered + x2 (LDS-staged) ----
__global__ void __launch_bounds__(256) prep_kernel(
    const float* __restrict__ X, const float* __restrict__ P,
    short* __restrict__ XgF, short* __restrict__ GbF,
    float* __restrict__ x2, float* __restrict__ hsum, float* __restrict__ hp2) {
    int t = threadIdx.x;
    int bx = blockIdx.x;

    if (bx >= GMAT_BLOCKS) {
        // ---------------- xprep: 32 rows, staged via LDS ----------------
        __shared__ float xs[32][260];
        int base = (bx - GMAT_BLOCKS) * 32;
        int row = t >> 3;   // 0..31
        int seg = t & 7;    // 8 segs x 32 floats
        const float4* src = reinterpret_cast<const float4*>(X + (size_t)(base + row) * D) + seg * 8;
        float sq = 0.f;
#pragma unroll
        for (int p = 0; p < 8; ++p) {
            float4 v = src[p];
            sq += v.x * v.x + v.y * v.y + v.z * v.z + v.w * v.w;
            *reinterpret_cast<float4*>(&xs[row][seg * 32 + p * 4]) = v;
        }
        sq += __shfl_xor(sq, 1);
        sq += __shfl_xor(sq, 2);
        sq += __shfl_xor(sq, 4);
        if (seg == 0) x2[base + row] = sq;
        __syncthreads();

        // frag phase: wave w -> row-group g = w&1 (16 rows), kg-half = w>>1
        int w = t >> 6, l = t & 63;
        int g = w & 1;
        int lr = g * 16 + (l & 15);
        int q = l >> 4;
        int Ng = (base >> 4) + g;
#pragma unroll
        for (int c = 0; c < 4; ++c) {
            int kg = (w >> 1) * 4 + c;
            const float* sp = &xs[lr][kg * 32 + q * 8];
            float4 a = *reinterpret_cast<const float4*>(sp);
            float4 b = *reinterpret_cast<const float4*>(sp + 4);
            short8 wv;
            wv[0] = f2bf(a.x); wv[1] = f2bf(a.y); wv[2] = f2bf(a.z); wv[3] = f2bf(a.w);
            wv[4] = f2bf(b.x); wv[5] = f2bf(b.y); wv[6] = f2bf(b.z); wv[7] = f2bf(b.w);
            *reinterpret_cast<short8*>(XgF + (((size_t)Ng * 8 + kg) << 9) + l * 8) = wv;
        }
        return;
    }

    // ---------------- gmat (R6 verbatim) ----------------
    __shared__ float ht[4][WJ];
    __shared__ int jrow[WJ];
    __shared__ __align__(16) float gpart[4][4][256];
    __shared__ float hqred[4][4];
    __shared__ float hsred[4][4];
    int i0 = bx * 4;
    int r0 = i0 >> 5, c0 = i0 & 31;

    for (int u = t; u < WJ; u += 256) {
        int jr = (r0 + (u / WC) - 6 + 32) & 31;
        int jc = (c0 + (u % WC) - 7 + 32) & 31;
        int j = jr * 32 + jc;
        jrow[u] = j;
#pragma unroll
        for (int s = 0; s < 4; ++s) ht[s][u] = hval(i0 + s, j);
    }
    __syncthreads();

    int w = t >> 6, lane = t & 63;
    int j0 = w * JSUB;
    int j1 = (j0 + JSUB < WJ) ? j0 + JSUB : WJ;
    f32x4 g[4] = {{0.f, 0.f, 0.f, 0.f}, {0.f, 0.f, 0.f, 0.f},
                  {0.f, 0.f, 0.f, 0.f}, {0.f, 0.f, 0.f, 0.f}};
    float hqp[4] = {0.f, 0.f, 0.f, 0.f};
    float hsp[4] = {0.f, 0.f, 0.f, 0.f};
    for (int u = j0; u < j1; ++u) {
        f32x4 pv = *reinterpret_cast<const f32x4*>(P + (size_t)jrow[u] * D + lane * 4);
        float q = pv[0] * pv[0] + pv[1] * pv[1] + pv[2] * pv[2] + pv[3] * pv[3];
#pragma unroll
        for (int s = 0; s < 4; ++s) {
            float h = ht[s][u];
            g[s][0] = fmaf(h, pv[0], g[s][0]);
            g[s][1] = fmaf(h, pv[1], g[s][1]);
            g[s][2] = fmaf(h, pv[2], g[s][2]);
            g[s][3] = fmaf(h, pv[3], g[s][3]);
            hqp[s] = fmaf(h, q, hqp[s]);
            hsp[s] += h;
        }
    }
#pragma unroll
    for (int s = 0; s < 4; ++s)
        *reinterpret_cast<f32x4*>(&gpart[w][s][lane * 4]) = g[s];
#pragma unroll
    for (int s = 0; s < 4; ++s) {
#pragma unroll
        for (int off = 1; off < 64; off <<= 1) hqp[s] += __shfl_xor(hqp[s], off);
    }
    if (lane == 0) {
#pragma unroll
        for (int s = 0; s < 4; ++s) { hqred[w][s] = hqp[s]; hsred[w][s] = hsp[s]; }
    }
    __syncthreads();

    {
        int s = t >> 6;
        f32x4 gs = *reinterpret_cast<const f32x4*>(&gpart[0][s][lane * 4]);
#pragma unroll
        for (int ww = 1; ww < 4; ++ww) {
            f32x4 gp = *reinterpret_cast<const f32x4*>(&gpart[ww][s][lane * 4]);
            gs[0] += gp[0]; gs[1] += gp[1]; gs[2] += gp[2]; gs[3] += gp[3];
        }
        float h0 = __shfl_down(gs[0], 1);
        float h1 = __shfl_down(gs[1], 1);
        float h2 = __shfl_down(gs[2], 1);
        float h3 = __shfl_down(gs[3], 1);
        if (!(lane & 1)) {
            int c = lane >> 1;
            int kg = c >> 2;
            int q = c & 3;
            int i = i0 + s;
            int Ig = i >> 4;
            short8 wv;
            wv[0] = f2bf(gs[0]); wv[1] = f2bf(gs[1]); wv[2] = f2bf(gs[2]); wv[3] = f2bf(gs[3]);
            wv[4] = f2bf(h0);    wv[5] = f2bf(h1);    wv[6] = f2bf(h2);    wv[7] = f2bf(h3);
            *reinterpret_cast<short8*>(
                GbF + (((size_t)Ig * 8 + kg) << 9) + ((i & 15) + 16 * q) * 8) = wv;
        }
    }
    if (t < 4) {
        hsum[i0 + t] = hsred[0][t] + hsred[1][t] + hsred[2][t] + hsred[3][t];
    } else if (t < 8) {
        int s = t - 4;
        hp2[i0 + s] = hqred[0][s] + hqred[1][s] + hqred[2][s] + hqred[3][s];
    }
}

// ---- som9: 256 blocks x 512 thr. 8 waves = 2 row-groups(32n) x 4 i-quarters
//      (256i each). A in registers for the whole kernel (16 short8/wave,
//      coalesced frag loads); B streamed from L2 as fragment dwordx4.
//      NO LDS / NO barriers in the K-loop — compiler schedules loads.
//      i-chunk 32: acc reset + rmin fold per chunk. Direct store, no atomics.
__global__ void __launch_bounds__(512, 2) som9_kernel(
    const short* __restrict__ XgF, const short* __restrict__ GbF,
    const float* __restrict__ x2, const float* __restrict__ hsum,
    const float* __restrict__ hp2, float* __restrict__ out) {
    __shared__ float red[4][64];

    const int t = threadIdx.x;
    const int l = t & 63;
    const int wid = t >> 6;
    const int rg = wid >> 2;   // row-group (32 rows)
    const int iq = wid & 3;    // i-quarter (256 i)
    const int lm = l & 15;
    const int lq = l >> 4;
    const int n0 = blockIdx.x * 64;

    // ---- A fragments, resident all kernel: A_[kt][kk][m] ----
    short8 A_[4][2][2];
    const int NgBase = (n0 >> 4) + rg * 2;
#pragma unroll
    for (int kt = 0; kt < 4; ++kt)
#pragma unroll
        for (int kk = 0; kk < 2; ++kk)
#pragma unroll
            for (int m = 0; m < 2; ++m)
                A_[kt][kk][m] = *reinterpret_cast<const short8*>(
                    XgF + (((size_t)(NgBase + m) * 8 + kt * 2 + kk) << 9) + l * 8);

    // ---- epilogue constants preloaded ----
    float hs_[8][2], hq_[8][2];
#pragma unroll
    for (int ic = 0; ic < 8; ++ic)
#pragma unroll
        for (int n = 0; n < 2; ++n) {
            int ig = iq * 256 + ic * 32 + n * 16 + lm;
            hs_[ic][n] = hsum[ig];
            hq_[ic][n] = hp2[ig];
        }
    float x2v[2][4];
#pragma unroll
    for (int m = 0; m < 2; ++m)
#pragma unroll
        for (int j = 0; j < 4; ++j)
            x2v[m][j] = x2[n0 + rg * 32 + m * 16 + lq * 4 + j];

    float rmin[2][4];
#pragma unroll
    for (int m = 0; m < 2; ++m)
#pragma unroll
        for (int j = 0; j < 4; ++j) rmin[m][j] = 3.4e38f;

    // ---- main loop: 8 i-chunks x 4 kt, fully unrolled, barrier-free ----
#pragma unroll
    for (int ic = 0; ic < 8; ++ic) {
        f32x4 acc[2][2];
#pragma unroll
        for (int m = 0; m < 2; ++m)
#pragma unroll
            for (int n = 0; n < 2; ++n) acc[m][n] = (f32x4){0.f, 0.f, 0.f, 0.f};
#pragma unroll
        for (int kt = 0; kt < 4; ++kt) {
            short8 b[2][2];
#pragma unroll
            for (int n = 0; n < 2; ++n)
#pragma unroll
                for (int kk = 0; kk < 2; ++kk)
                    b[n][kk] = *reinterpret_cast<const short8*>(
                        GbF + (((size_t)(iq * 16 + ic * 2 + n) * 8 + kt * 2 + kk) << 9) + l * 8);
#pragma unroll
            for (int m = 0; m < 2; ++m)
#pragma unroll
                for (int n = 0; n < 2; ++n)
#pragma unroll
                    for (int kk = 0; kk < 2; ++kk)
                        acc[m][n] = __builtin_amdgcn_mfma_f32_16x16x32_bf16(
                            A_[kt][kk][m], b[n][kk], acc[m][n], 0, 0, 0);
        }
        // fold: e = hs*x2 + hq - 2*acc
#pragma unroll
        for (int n = 0; n < 2; ++n) {
            float hs = hs_[ic][n], hq = hq_[ic][n];
#pragma unroll
            for (int m = 0; m < 2; ++m)
#pragma unroll
                for (int j = 0; j < 4; ++j) {
                    float e = fmaf(hs, x2v[m][j], hq) - 2.0f * acc[m][n][j];
                    rmin[m][j] = fminf(rmin[m][j], e);
                }
        }
    }

    // ---- min across the 16 lm lanes ----
#pragma unroll
    for (int m = 0; m < 2; ++m)
#pragma unroll
        for (int j = 0; j < 4; ++j) {
            float v = rmin[m][j];
            v = fminf(v, __shfl_xor(v, 1));
            v = fminf(v, __shfl_xor(v, 2));
            v = fminf(v, __shfl_xor(v, 4));
            v = fminf(v, __shfl_xor(v, 8));
            rmin[m][j] = v;
        }
    if (lm == 0) {
#pragma unroll
        for (int m = 0; m < 2; ++m)
#pragma unroll
            for (int j = 0; j < 4; ++j)
                red[iq][rg * 32 + m * 16 + lq * 4 + j] = rmin[m][j];
    }
    __syncthreads();
    if (t < 64) {
        float v = fminf(fminf(red[0][t], red[1][t]), fminf(red[2][t], red[3][t]));
        out[n0 + t] = 0.5f * v;
    }
}

extern "C" void kernel_launch(void* const* d_in, const int* in_sizes, int n_in,
                              void* d_out, int out_size, void* d_ws, size_t ws_size,
                              hipStream_t stream) {
    const float* X = (const float*)d_in[0];  // [16384, 256]
    const float* P = (const float*)d_in[1];  // [1024, 256]
    float* out = (float*)d_out;              // [1, 16384]
    int N = in_sizes[0] / D;                 // 16384

    float* ws = (float*)d_ws;
    float* hsum = ws + 1024;             // 1024 f32
    float* hp2 = ws + 2048;              // 1024 f32
    float* x2 = ws + 4096;               // 16384 f32
    short* GbF = (short*)(ws + 32768);   // 1024*256 bf16 frag-ordered (512KB)
    short* XgF = (short*)(ws + 262144);  // 16384*256 bf16 frag-ordered (8.4MB)

    prep_kernel<<<GMAT_BLOCKS + XPREP_BLOCKS, 256, 0, stream>>>(
        X, P, XgF, GbF, x2, hsum, hp2);
    som9_kernel<<<N / 64, 512, 0, stream>>>(XgF, GbF, x2, hsum, hp2, out);
}